// Round 1
// baseline (1022.589 us; speedup 1.0000x reference)
//
#include <hip/hip_runtime.h>

#define N_NODES 100000
#define N_EDGES 800000
#define NEG 0.2f

// ---------------------------------------------------------------------------
// Kernel 1: fused h = x @ W (both directions) + per-node attention logits.
// grid = (ceil(N/64), 2), block = 256. W (128x128 f32 = 64KB) staged in LDS.
// Each thread: 2 rows (r, r+32) x 16 cols (one head) -> alpha reduction is
// thread-local (head = tid & 7 owns cols [head*16, head*16+16)).
// ---------------------------------------------------------------------------
__global__ __launch_bounds__(256) void gemm_alpha_kernel(
    const float* __restrict__ x,
    const float* __restrict__ W_in, const float* __restrict__ W_out,
    const float* __restrict__ as_in, const float* __restrict__ ad_in,
    const float* __restrict__ as_out, const float* __restrict__ ad_out,
    float* __restrict__ h_in, float* __restrict__ h_out,
    float* __restrict__ asrc_in, float* __restrict__ adst_in,
    float* __restrict__ asrc_out, float* __restrict__ adst_out)
{
    __shared__ float Ws[128 * 128];

    const int dir = blockIdx.y;
    const float* W    = dir ? W_out  : W_in;
    const float* av_s = dir ? as_out : as_in;
    const float* av_d = dir ? ad_out : ad_in;
    float* h    = dir ? h_out    : h_in;
    float* asrc = dir ? asrc_out : asrc_in;
    float* adst = dir ? adst_out : adst_in;

    const int tid = threadIdx.x;
    // cooperative load of W into LDS, coalesced float4
    for (int i = tid * 4; i < 128 * 128; i += 256 * 4) {
        *(float4*)(&Ws[i]) = *(const float4*)(&W[i]);
    }
    __syncthreads();

    const int r0   = blockIdx.x * 64 + (tid >> 3);
    const int r1   = r0 + 32;
    const int head = tid & 7;
    const int c0   = head * 16;

    float acc0[16], acc1[16];
#pragma unroll
    for (int i = 0; i < 16; ++i) { acc0[i] = 0.f; acc1[i] = 0.f; }

    const bool v0 = (r0 < N_NODES), v1 = (r1 < N_NODES);
    const float* xr0 = x + (long long)r0 * 128;
    const float* xr1 = x + (long long)r1 * 128;

    for (int k4 = 0; k4 < 32; ++k4) {
        float4 x0 = v0 ? *(const float4*)(&xr0[k4 * 4]) : float4{0.f, 0.f, 0.f, 0.f};
        float4 x1 = v1 ? *(const float4*)(&xr1[k4 * 4]) : float4{0.f, 0.f, 0.f, 0.f};
        float xv0[4] = {x0.x, x0.y, x0.z, x0.w};
        float xv1[4] = {x1.x, x1.y, x1.z, x1.w};
#pragma unroll
        for (int kk = 0; kk < 4; ++kk) {
            const float* wrow = &Ws[(k4 * 4 + kk) * 128 + c0];
            float4 wa = *(const float4*)(&wrow[0]);
            float4 wb = *(const float4*)(&wrow[4]);
            float4 wc = *(const float4*)(&wrow[8]);
            float4 wd = *(const float4*)(&wrow[12]);
            float wv[16] = {wa.x, wa.y, wa.z, wa.w,
                            wb.x, wb.y, wb.z, wb.w,
                            wc.x, wc.y, wc.z, wc.w,
                            wd.x, wd.y, wd.z, wd.w};
#pragma unroll
            for (int c = 0; c < 16; ++c) {
                acc0[c] += xv0[kk] * wv[c];
                acc1[c] += xv1[kk] * wv[c];
            }
        }
    }

    // epilogue: alpha_src / alpha_dst reductions (thread-local: one head)
    float s0 = 0.f, d0 = 0.f, s1 = 0.f, d1 = 0.f;
#pragma unroll
    for (int c = 0; c < 16; ++c) {
        const float ac = av_s[c0 + c];
        const float dc = av_d[c0 + c];
        s0 += acc0[c] * ac;  d0 += acc0[c] * dc;
        s1 += acc1[c] * ac;  d1 += acc1[c] * dc;
    }
    if (v0) {
        float* hp = &h[(long long)r0 * 128 + c0];
        *(float4*)(&hp[0])  = float4{acc0[0],  acc0[1],  acc0[2],  acc0[3]};
        *(float4*)(&hp[4])  = float4{acc0[4],  acc0[5],  acc0[6],  acc0[7]};
        *(float4*)(&hp[8])  = float4{acc0[8],  acc0[9],  acc0[10], acc0[11]};
        *(float4*)(&hp[12]) = float4{acc0[12], acc0[13], acc0[14], acc0[15]};
        asrc[r0 * 8 + head] = s0;
        adst[r0 * 8 + head] = d0;
    }
    if (v1) {
        float* hp = &h[(long long)r1 * 128 + c0];
        *(float4*)(&hp[0])  = float4{acc1[0],  acc1[1],  acc1[2],  acc1[3]};
        *(float4*)(&hp[4])  = float4{acc1[4],  acc1[5],  acc1[6],  acc1[7]};
        *(float4*)(&hp[8])  = float4{acc1[8],  acc1[9],  acc1[10], acc1[11]};
        *(float4*)(&hp[12]) = float4{acc1[12], acc1[13], acc1[14], acc1[15]};
        asrc[r1 * 8 + head] = s1;
        adst[r1 * 8 + head] = d1;
    }
}

// ---------------------------------------------------------------------------
// Kernel 2: init out = b_in + b_out (broadcast over rows); zero denominators.
// ---------------------------------------------------------------------------
__global__ __launch_bounds__(256) void init_kernel(
    const float* __restrict__ b_in, const float* __restrict__ b_out,
    float* __restrict__ out, float* __restrict__ denom_in, float* __restrict__ denom_out)
{
    const int idx = blockIdx.x * 256 + threadIdx.x;
    if (idx < N_NODES * 128) {
        out[idx] = b_in[idx & 127] + b_out[idx & 127];
    }
    if (idx < N_NODES * 8) {
        denom_in[idx]  = 0.f;
        denom_out[idx] = 0.f;
    }
}

// ---------------------------------------------------------------------------
// Kernel 3: softmax denominators per (dst node, head), both directions.
// No segment_max needed: logits are O(1), exp() is safe in f32 and the
// softmax value is invariant to the max shift.
// One thread per (edge, head): 2 atomics each.
// ---------------------------------------------------------------------------
__global__ __launch_bounds__(256) void edge_denom_kernel(
    const int* __restrict__ ei,
    const float* __restrict__ asrc_in, const float* __restrict__ adst_in,
    const float* __restrict__ asrc_out, const float* __restrict__ adst_out,
    float* __restrict__ denom_in, float* __restrict__ denom_out)
{
    const int idx = blockIdx.x * 256 + threadIdx.x;
    if (idx >= N_EDGES * 8) return;
    const int e  = idx >> 3;
    const int hh = idx & 7;
    const int s = ei[e];
    const int t = ei[N_EDGES + e];

    // conv_in: message s -> t, softmax grouped by t
    float lin = asrc_in[s * 8 + hh] + adst_in[t * 8 + hh];
    lin = lin > 0.f ? lin : NEG * lin;
    atomicAdd(&denom_in[t * 8 + hh], __expf(lin));

    // conv_out (flipped): message t -> s, softmax grouped by s
    float lo = asrc_out[t * 8 + hh] + adst_out[s * 8 + hh];
    lo = lo > 0.f ? lo : NEG * lo;
    atomicAdd(&denom_out[s * 8 + hh], __expf(lo));
}

// ---------------------------------------------------------------------------
// Kernel 4: scatter messages. One thread per (edge, output col j in 0..127).
// Recomputes exp (cheap, v_exp_f32) instead of storing per-edge weights.
// ---------------------------------------------------------------------------
__global__ __launch_bounds__(256) void edge_scatter_kernel(
    const int* __restrict__ ei,
    const float* __restrict__ h_in, const float* __restrict__ h_out,
    const float* __restrict__ asrc_in, const float* __restrict__ adst_in,
    const float* __restrict__ asrc_out, const float* __restrict__ adst_out,
    const float* __restrict__ denom_in, const float* __restrict__ denom_out,
    float* __restrict__ out)
{
    const int idx = blockIdx.x * 256 + threadIdx.x;
    if (idx >= N_EDGES * 128) return;
    const int e  = idx >> 7;
    const int j  = idx & 127;
    const int hh = j >> 4;
    const int s = ei[e];
    const int t = ei[N_EDGES + e];

    float lin = asrc_in[s * 8 + hh] + adst_in[t * 8 + hh];
    lin = lin > 0.f ? lin : NEG * lin;
    const float cin = __expf(lin) / denom_in[t * 8 + hh];
    atomicAdd(&out[(long long)t * 128 + j], h_in[(long long)s * 128 + j] * cin);

    float lo = asrc_out[t * 8 + hh] + adst_out[s * 8 + hh];
    lo = lo > 0.f ? lo : NEG * lo;
    const float cout = __expf(lo) / denom_out[s * 8 + hh];
    atomicAdd(&out[(long long)s * 128 + j], h_out[(long long)t * 128 + j] * cout);
}

extern "C" void kernel_launch(void* const* d_in, const int* in_sizes, int n_in,
                              void* d_out, int out_size, void* d_ws, size_t ws_size,
                              hipStream_t stream) {
    const float* x      = (const float*)d_in[0];
    const int*   ei     = (const int*)  d_in[1];
    const float* W_in   = (const float*)d_in[2];
    const float* as_in  = (const float*)d_in[3];
    const float* ad_in  = (const float*)d_in[4];
    const float* b_in   = (const float*)d_in[5];
    const float* W_out  = (const float*)d_in[6];
    const float* as_out = (const float*)d_in[7];
    const float* ad_out = (const float*)d_in[8];
    const float* b_out  = (const float*)d_in[9];
    float* out = (float*)d_out;

    // workspace layout (floats): ~121.6 MB total
    float* ws = (float*)d_ws;
    const long long NH = (long long)N_NODES * 128;
    float* h_in      = ws;
    float* h_out     = h_in + NH;
    float* asrc_in   = h_out + NH;
    float* adst_in   = asrc_in + N_NODES * 8;
    float* asrc_out  = adst_in + N_NODES * 8;
    float* adst_out  = asrc_out + N_NODES * 8;
    float* denom_in  = adst_out + N_NODES * 8;
    float* denom_out = denom_in + N_NODES * 8;

    dim3 gemm_grid((N_NODES + 63) / 64, 2);
    gemm_alpha_kernel<<<gemm_grid, 256, 0, stream>>>(
        x, W_in, W_out, as_in, ad_in, as_out, ad_out,
        h_in, h_out, asrc_in, adst_in, asrc_out, adst_out);

    init_kernel<<<(N_NODES * 128 + 255) / 256, 256, 0, stream>>>(
        b_in, b_out, out, denom_in, denom_out);

    edge_denom_kernel<<<(N_EDGES * 8 + 255) / 256, 256, 0, stream>>>(
        ei, asrc_in, adst_in, asrc_out, adst_out, denom_in, denom_out);

    edge_scatter_kernel<<<(N_EDGES * 128 + 255) / 256, 256, 0, stream>>>(
        ei, h_in, h_out, asrc_in, adst_in, asrc_out, adst_out,
        denom_in, denom_out, out);
}

// Round 2
// 657.670 us; speedup vs baseline: 1.5549x; 1.5549x over previous
//
#include <hip/hip_runtime.h>

#define N_NODES 100000
#define N_EDGES 800000
#define NEG 0.2f
#define SCAN_B 256
#define SCAN_NB ((N_NODES + SCAN_B - 1) / SCAN_B)   // 391

// ---------------------------------------------------------------------------
// Kernel 1: fused h = x @ W (both directions) + per-node attention logits.
// ---------------------------------------------------------------------------
__global__ __launch_bounds__(256) void gemm_alpha_kernel(
    const float* __restrict__ x,
    const float* __restrict__ W_in, const float* __restrict__ W_out,
    const float* __restrict__ as_in, const float* __restrict__ ad_in,
    const float* __restrict__ as_out, const float* __restrict__ ad_out,
    float* __restrict__ h_in, float* __restrict__ h_out,
    float* __restrict__ asrc_in, float* __restrict__ adst_in,
    float* __restrict__ asrc_out, float* __restrict__ adst_out)
{
    __shared__ float Ws[128 * 128];

    const int dir = blockIdx.y;
    const float* W    = dir ? W_out  : W_in;
    const float* av_s = dir ? as_out : as_in;
    const float* av_d = dir ? ad_out : ad_in;
    float* h    = dir ? h_out    : h_in;
    float* asrc = dir ? asrc_out : asrc_in;
    float* adst = dir ? adst_out : adst_in;

    const int tid = threadIdx.x;
    for (int i = tid * 4; i < 128 * 128; i += 256 * 4) {
        *(float4*)(&Ws[i]) = *(const float4*)(&W[i]);
    }
    __syncthreads();

    const int r0   = blockIdx.x * 64 + (tid >> 3);
    const int r1   = r0 + 32;
    const int head = tid & 7;
    const int c0   = head * 16;

    float acc0[16], acc1[16];
#pragma unroll
    for (int i = 0; i < 16; ++i) { acc0[i] = 0.f; acc1[i] = 0.f; }

    const bool v0 = (r0 < N_NODES), v1 = (r1 < N_NODES);
    const float* xr0 = x + (long long)r0 * 128;
    const float* xr1 = x + (long long)r1 * 128;

    for (int k4 = 0; k4 < 32; ++k4) {
        float4 x0 = v0 ? *(const float4*)(&xr0[k4 * 4]) : float4{0.f, 0.f, 0.f, 0.f};
        float4 x1 = v1 ? *(const float4*)(&xr1[k4 * 4]) : float4{0.f, 0.f, 0.f, 0.f};
        float xv0[4] = {x0.x, x0.y, x0.z, x0.w};
        float xv1[4] = {x1.x, x1.y, x1.z, x1.w};
#pragma unroll
        for (int kk = 0; kk < 4; ++kk) {
            const float* wrow = &Ws[(k4 * 4 + kk) * 128 + c0];
            float4 wa = *(const float4*)(&wrow[0]);
            float4 wb = *(const float4*)(&wrow[4]);
            float4 wc = *(const float4*)(&wrow[8]);
            float4 wd = *(const float4*)(&wrow[12]);
            float wv[16] = {wa.x, wa.y, wa.z, wa.w,
                            wb.x, wb.y, wb.z, wb.w,
                            wc.x, wc.y, wc.z, wc.w,
                            wd.x, wd.y, wd.z, wd.w};
#pragma unroll
            for (int c = 0; c < 16; ++c) {
                acc0[c] += xv0[kk] * wv[c];
                acc1[c] += xv1[kk] * wv[c];
            }
        }
    }

    float s0 = 0.f, d0 = 0.f, s1 = 0.f, d1 = 0.f;
#pragma unroll
    for (int c = 0; c < 16; ++c) {
        const float ac = av_s[c0 + c];
        const float dc = av_d[c0 + c];
        s0 += acc0[c] * ac;  d0 += acc0[c] * dc;
        s1 += acc1[c] * ac;  d1 += acc1[c] * dc;
    }
    if (v0) {
        float* hp = &h[(long long)r0 * 128 + c0];
        *(float4*)(&hp[0])  = float4{acc0[0],  acc0[1],  acc0[2],  acc0[3]};
        *(float4*)(&hp[4])  = float4{acc0[4],  acc0[5],  acc0[6],  acc0[7]};
        *(float4*)(&hp[8])  = float4{acc0[8],  acc0[9],  acc0[10], acc0[11]};
        *(float4*)(&hp[12]) = float4{acc0[12], acc0[13], acc0[14], acc0[15]};
        asrc[r0 * 8 + head] = s0;
        adst[r0 * 8 + head] = d0;
    }
    if (v1) {
        float* hp = &h[(long long)r1 * 128 + c0];
        *(float4*)(&hp[0])  = float4{acc1[0],  acc1[1],  acc1[2],  acc1[3]};
        *(float4*)(&hp[4])  = float4{acc1[4],  acc1[5],  acc1[6],  acc1[7]};
        *(float4*)(&hp[8])  = float4{acc1[8],  acc1[9],  acc1[10], acc1[11]};
        *(float4*)(&hp[12]) = float4{acc1[12], acc1[13], acc1[14], acc1[15]};
        asrc[r1 * 8 + head] = s1;
        adst[r1 * 8 + head] = d1;
    }
}

// ---------------------------------------------------------------------------
// CSR build: zero -> histogram -> scan (3 stages) -> scatter adjacency
// ---------------------------------------------------------------------------
__global__ __launch_bounds__(256) void zero_cnt_kernel(int* __restrict__ cnt_in,
                                                       int* __restrict__ cnt_out)
{
    const int i = blockIdx.x * 256 + threadIdx.x;
    if (i < N_NODES) { cnt_in[i] = 0; cnt_out[i] = 0; }
}

__global__ __launch_bounds__(256) void hist_kernel(const int* __restrict__ ei,
                                                   int* __restrict__ cnt_in,
                                                   int* __restrict__ cnt_out)
{
    const int e = blockIdx.x * 256 + threadIdx.x;
    if (e >= N_EDGES) return;
    const int s = ei[e];
    const int t = ei[N_EDGES + e];
    atomicAdd(&cnt_in[t], 1);    // conv_in rows grouped by dst t
    atomicAdd(&cnt_out[s], 1);   // conv_out rows grouped by src s
}

// stage 1: per-block inclusive scan -> exclusive-within-block + block totals
__global__ __launch_bounds__(SCAN_B) void scan1_kernel(
    const int* __restrict__ cnt_in, const int* __restrict__ cnt_out,
    int* __restrict__ pre_in, int* __restrict__ pre_out,
    int* __restrict__ part_in, int* __restrict__ part_out)
{
    const int dir = blockIdx.y;
    const int* cnt = dir ? cnt_out : cnt_in;
    int* pre  = dir ? pre_out  : pre_in;
    int* part = dir ? part_out : part_in;

    __shared__ int sm[SCAN_B];
    const int tid = threadIdx.x;
    const int i = blockIdx.x * SCAN_B + tid;
    const int v = (i < N_NODES) ? cnt[i] : 0;
    sm[tid] = v;
    __syncthreads();
#pragma unroll
    for (int off = 1; off < SCAN_B; off <<= 1) {
        int t = (tid >= off) ? sm[tid - off] : 0;
        __syncthreads();
        sm[tid] += t;
        __syncthreads();
    }
    if (i < N_NODES) pre[i] = sm[tid] - v;            // exclusive within block
    if (tid == SCAN_B - 1) part[blockIdx.x] = sm[tid]; // block total
}

// stage 2: scan the block totals (single block, both dirs)
__global__ __launch_bounds__(512) void scan2_kernel(int* __restrict__ part_in,
                                                    int* __restrict__ part_out)
{
    const int dir = blockIdx.x;
    int* part = dir ? part_out : part_in;
    __shared__ int sm[512];
    const int tid = threadIdx.x;
    const int v = (tid < SCAN_NB) ? part[tid] : 0;
    sm[tid] = v;
    __syncthreads();
#pragma unroll
    for (int off = 1; off < 512; off <<= 1) {
        int t = (tid >= off) ? sm[tid - off] : 0;
        __syncthreads();
        sm[tid] += t;
        __syncthreads();
    }
    if (tid < SCAN_NB) part[tid] = sm[tid] - v;        // exclusive
}

// stage 3: finalize offsets; also init cursor arrays (reuse cnt storage)
__global__ __launch_bounds__(SCAN_B) void scan3_kernel(
    const int* __restrict__ pre_in, const int* __restrict__ pre_out,
    const int* __restrict__ part_in, const int* __restrict__ part_out,
    int* __restrict__ offs_in, int* __restrict__ offs_out,
    int* __restrict__ cur_in, int* __restrict__ cur_out)
{
    const int dir = blockIdx.y;
    const int* pre  = dir ? pre_out  : pre_in;
    const int* part = dir ? part_out : part_in;
    int* offs = dir ? offs_out : offs_in;
    int* cur  = dir ? cur_out  : cur_in;

    const int i = blockIdx.x * SCAN_B + threadIdx.x;
    if (i < N_NODES) {
        const int o = pre[i] + part[blockIdx.x];
        offs[i] = o;
        cur[i]  = o;
    }
    if (i == 0 && dir == 0) { offs_in[N_NODES] = N_EDGES; offs_out[N_NODES] = N_EDGES; }
}

__global__ __launch_bounds__(256) void scatter_adj_kernel(
    const int* __restrict__ ei,
    int* __restrict__ cur_in, int* __restrict__ cur_out,
    int* __restrict__ adj_in, int* __restrict__ adj_out)
{
    const int e = blockIdx.x * 256 + threadIdx.x;
    if (e >= N_EDGES) return;
    const int s = ei[e];
    const int t = ei[N_EDGES + e];
    adj_in[atomicAdd(&cur_in[t], 1)]  = s;  // row t holds src neighbors
    adj_out[atomicAdd(&cur_out[s], 1)] = t; // row s holds dst neighbors
}

// ---------------------------------------------------------------------------
// Gather: one wave per node, both directions + bias. No atomics.
// lane -> cols (2*lane, 2*lane+1), head = lane>>3.
// num/den accumulated in registers; out written once as float2.
// ---------------------------------------------------------------------------
__global__ __launch_bounds__(256) void gather_kernel(
    const int* __restrict__ offs_in, const int* __restrict__ adj_in,
    const int* __restrict__ offs_out, const int* __restrict__ adj_out,
    const float* __restrict__ h_in, const float* __restrict__ h_out,
    const float* __restrict__ asrc_in, const float* __restrict__ adst_in,
    const float* __restrict__ asrc_out, const float* __restrict__ adst_out,
    const float* __restrict__ b_in, const float* __restrict__ b_out,
    float* __restrict__ out)
{
    const int n = (blockIdx.x * 256 + threadIdx.x) >> 6;
    if (n >= N_NODES) return;
    const int lane = threadIdx.x & 63;
    const int c0 = lane * 2;
    const int hh = lane >> 3;

    float acc0 = b_in[c0] + b_out[c0];
    float acc1 = b_in[c0 + 1] + b_out[c0 + 1];

    // direction "in": group by dst=n, neighbors are src
    {
        const int beg = offs_in[n], end = offs_in[n + 1];
        if (end > beg) {
            const float ad = adst_in[n * 8 + hh];
            float num0 = 0.f, num1 = 0.f, den = 0.f;
            for (int p = beg; p < end; ++p) {
                const int nbr = adj_in[p];
                float l = asrc_in[nbr * 8 + hh] + ad;
                l = l > 0.f ? l : NEG * l;
                const float w = __expf(l);
                den += w;
                const float2 hv = *(const float2*)&h_in[(long long)nbr * 128 + c0];
                num0 += w * hv.x;
                num1 += w * hv.y;
            }
            acc0 += num0 / den;
            acc1 += num1 / den;
        }
    }
    // direction "out": group by src=n, neighbors are dst (flipped edges)
    {
        const int beg = offs_out[n], end = offs_out[n + 1];
        if (end > beg) {
            const float ad = adst_out[n * 8 + hh];
            float num0 = 0.f, num1 = 0.f, den = 0.f;
            for (int p = beg; p < end; ++p) {
                const int nbr = adj_out[p];
                float l = asrc_out[nbr * 8 + hh] + ad;
                l = l > 0.f ? l : NEG * l;
                const float w = __expf(l);
                den += w;
                const float2 hv = *(const float2*)&h_out[(long long)nbr * 128 + c0];
                num0 += w * hv.x;
                num1 += w * hv.y;
            }
            acc0 += num0 / den;
            acc1 += num1 / den;
        }
    }
    *(float2*)&out[(long long)n * 128 + c0] = float2{acc0, acc1};
}

extern "C" void kernel_launch(void* const* d_in, const int* in_sizes, int n_in,
                              void* d_out, int out_size, void* d_ws, size_t ws_size,
                              hipStream_t stream) {
    const float* x      = (const float*)d_in[0];
    const int*   ei     = (const int*)  d_in[1];
    const float* W_in   = (const float*)d_in[2];
    const float* as_in  = (const float*)d_in[3];
    const float* ad_in  = (const float*)d_in[4];
    const float* b_in   = (const float*)d_in[5];
    const float* W_out  = (const float*)d_in[6];
    const float* as_out = (const float*)d_in[7];
    const float* ad_out = (const float*)d_in[8];
    const float* b_out  = (const float*)d_in[9];
    float* out = (float*)d_out;

    // workspace layout
    char* ws = (char*)d_ws;
    const long long NH = (long long)N_NODES * 128;
    float* h_in      = (float*)ws;                  ws += NH * 4;
    float* h_out     = (float*)ws;                  ws += NH * 4;
    float* asrc_in   = (float*)ws;                  ws += N_NODES * 8 * 4;
    float* adst_in   = (float*)ws;                  ws += N_NODES * 8 * 4;
    float* asrc_out  = (float*)ws;                  ws += N_NODES * 8 * 4;
    float* adst_out  = (float*)ws;                  ws += N_NODES * 8 * 4;
    int* adj_in      = (int*)ws;                    ws += N_EDGES * 4;
    int* adj_out     = (int*)ws;                    ws += N_EDGES * 4;
    int* offs_in     = (int*)ws;                    ws += (N_NODES + 1) * 4;
    int* offs_out    = (int*)ws;                    ws += (N_NODES + 1) * 4;
    int* cnt_in      = (int*)ws;                    ws += N_NODES * 4;   // reused as cursors
    int* cnt_out     = (int*)ws;                    ws += N_NODES * 4;
    int* pre_in      = (int*)ws;                    ws += N_NODES * 4;
    int* pre_out     = (int*)ws;                    ws += N_NODES * 4;
    int* part_in     = (int*)ws;                    ws += SCAN_NB * 4;
    int* part_out    = (int*)ws;                    ws += SCAN_NB * 4;

    dim3 gemm_grid((N_NODES + 63) / 64, 2);
    gemm_alpha_kernel<<<gemm_grid, 256, 0, stream>>>(
        x, W_in, W_out, as_in, ad_in, as_out, ad_out,
        h_in, h_out, asrc_in, adst_in, asrc_out, adst_out);

    zero_cnt_kernel<<<(N_NODES + 255) / 256, 256, 0, stream>>>(cnt_in, cnt_out);
    hist_kernel<<<(N_EDGES + 255) / 256, 256, 0, stream>>>(ei, cnt_in, cnt_out);
    scan1_kernel<<<dim3(SCAN_NB, 2), SCAN_B, 0, stream>>>(
        cnt_in, cnt_out, pre_in, pre_out, part_in, part_out);
    scan2_kernel<<<2, 512, 0, stream>>>(part_in, part_out);
    scan3_kernel<<<dim3(SCAN_NB, 2), SCAN_B, 0, stream>>>(
        pre_in, pre_out, part_in, part_out, offs_in, offs_out, cnt_in, cnt_out);
    scatter_adj_kernel<<<(N_EDGES + 255) / 256, 256, 0, stream>>>(
        ei, cnt_in, cnt_out, adj_in, adj_out);

    gather_kernel<<<(N_NODES * 64 + 255) / 256, 256, 0, stream>>>(
        offs_in, adj_in, offs_out, adj_out, h_in, h_out,
        asrc_in, adst_in, asrc_out, adst_out, b_in, b_out, out);
}

// Round 3
// 531.722 us; speedup vs baseline: 1.9232x; 1.2369x over previous
//
#include <hip/hip_runtime.h>

#define N_NODES 100000
#define N_EDGES 800000
#define NEG 0.2f
#define SCAN_B 256
#define SCAN_NB ((N_NODES + SCAN_B - 1) / SCAN_B)   // 391
#define WT_S 136   // LDS row stride for transposed W (bf16): 128 + 8 pad

typedef __attribute__((ext_vector_type(8))) short bf16x8;
typedef __attribute__((ext_vector_type(4))) float f32x4;

__device__ inline short f2bf(float f) {   // round-to-nearest-even f32 -> bf16
    unsigned u = __float_as_uint(f);
    u += 0x7fffu + ((u >> 16) & 1u);
    return (short)(u >> 16);
}
__device__ inline float bf2f_lo(unsigned u) { return __uint_as_float(u << 16); }
__device__ inline float bf2f_hi(unsigned u) { return __uint_as_float(u & 0xffff0000u); }

// ---------------------------------------------------------------------------
// Kernel 1: h = bf16(x) @ bf16(W) via MFMA, f32 accumulate, bf16 output.
// grid = (782, 2 dirs), block = 256 (4 waves). Block tile: 128 rows x 128 cols
// x K=128. Wave w handles rows [w*32, w*32+32) as two 16-row MFMA tiles.
// A-frag: A[m=lane&15][k=quad*8+j] loaded straight from x (f32->bf16).
// B-frag: B[k][n=lane&15] read from LDS Wt[n][k] (transposed, stride 136).
// C/D: col=lane&15, row=quad*4+reg.
// ---------------------------------------------------------------------------
__global__ __launch_bounds__(256) void gemm_kernel(
    const float* __restrict__ x,
    const float* __restrict__ W_in, const float* __restrict__ W_out,
    unsigned short* __restrict__ h_in, unsigned short* __restrict__ h_out)
{
    __shared__ unsigned short Wt[128 * WT_S];

    const int dir = blockIdx.y;
    const float* W = dir ? W_out : W_in;
    unsigned short* h = dir ? h_out : h_in;

    const int tid = threadIdx.x;
    // stage W -> LDS, transposed to Wt[n][k], bf16
    for (int i = tid * 4; i < 128 * 128; i += 256 * 4) {
        const int k = i >> 7, n = i & 127;
        const float4 w4 = *(const float4*)&W[i];
        Wt[(n + 0) * WT_S + k] = (unsigned short)f2bf(w4.x);
        Wt[(n + 1) * WT_S + k] = (unsigned short)f2bf(w4.y);
        Wt[(n + 2) * WT_S + k] = (unsigned short)f2bf(w4.z);
        Wt[(n + 3) * WT_S + k] = (unsigned short)f2bf(w4.w);
    }
    __syncthreads();

    const int lane = tid & 63;
    const int wave = tid >> 6;
    const int m16  = lane & 15;
    const int quad = lane >> 4;
    const int rbase = blockIdx.x * 128 + wave * 32;

    f32x4 acc[2][8];
#pragma unroll
    for (int rt = 0; rt < 2; ++rt)
#pragma unroll
        for (int ct = 0; ct < 8; ++ct)
            acc[rt][ct] = f32x4{0.f, 0.f, 0.f, 0.f};

#pragma unroll
    for (int kb = 0; kb < 4; ++kb) {
        const int k0 = kb * 32 + quad * 8;
        bf16x8 a[2];
#pragma unroll
        for (int rt = 0; rt < 2; ++rt) {
            const int r = rbase + rt * 16 + m16;
            if (r < N_NODES) {
                const float* xp = &x[(long long)r * 128 + k0];
                const float4 f0 = *(const float4*)xp;
                const float4 f1 = *(const float4*)(xp + 4);
                bf16x8 af;
                af[0] = f2bf(f0.x); af[1] = f2bf(f0.y);
                af[2] = f2bf(f0.z); af[3] = f2bf(f0.w);
                af[4] = f2bf(f1.x); af[5] = f2bf(f1.y);
                af[6] = f2bf(f1.z); af[7] = f2bf(f1.w);
                a[rt] = af;
            } else {
                a[rt] = bf16x8{0, 0, 0, 0, 0, 0, 0, 0};
            }
        }
#pragma unroll
        for (int ct = 0; ct < 8; ++ct) {
            const bf16x8 b = *(const bf16x8*)&Wt[(ct * 16 + m16) * WT_S + k0];
            acc[0][ct] = __builtin_amdgcn_mfma_f32_16x16x32_bf16(a[0], b, acc[0][ct], 0, 0, 0);
            acc[1][ct] = __builtin_amdgcn_mfma_f32_16x16x32_bf16(a[1], b, acc[1][ct], 0, 0, 0);
        }
    }

    // epilogue: store h as bf16. Lane holds col = ct*16 + m16, rows quad*4+r.
#pragma unroll
    for (int rt = 0; rt < 2; ++rt) {
#pragma unroll
        for (int r = 0; r < 4; ++r) {
            const int row = rbase + rt * 16 + quad * 4 + r;
            if (row < N_NODES) {
                unsigned short* hp = &h[(long long)row * 128 + m16];
#pragma unroll
                for (int ct = 0; ct < 8; ++ct)
                    hp[ct * 16] = (unsigned short)f2bf(acc[rt][ct][r]);
            }
        }
    }
}

// ---------------------------------------------------------------------------
// Kernel 2: per-node attention logits from bf16 h (f32 math).
// thread = (node, head); grid.y = dir.
// ---------------------------------------------------------------------------
__global__ __launch_bounds__(256) void alpha_kernel(
    const unsigned short* __restrict__ h_in, const unsigned short* __restrict__ h_out,
    const float* __restrict__ as_in, const float* __restrict__ ad_in,
    const float* __restrict__ as_out, const float* __restrict__ ad_out,
    float* __restrict__ asrc_in, float* __restrict__ adst_in,
    float* __restrict__ asrc_out, float* __restrict__ adst_out)
{
    const int idx = blockIdx.x * 256 + threadIdx.x;
    if (idx >= N_NODES * 8) return;
    const int dir = blockIdx.y;
    const int hh = idx & 7;

    const unsigned short* h = dir ? h_out : h_in;
    const float* as = (dir ? as_out : as_in) + hh * 16;
    const float* ad = (dir ? ad_out : ad_in) + hh * 16;
    const unsigned short* hp = &h[(long long)(idx >> 3) * 128 + hh * 16];

    float s = 0.f, d = 0.f;
#pragma unroll
    for (int g = 0; g < 4; ++g) {
        const uint2 hv = *(const uint2*)&hp[g * 4];
        const float v0 = bf2f_lo(hv.x), v1 = bf2f_hi(hv.x);
        const float v2 = bf2f_lo(hv.y), v3 = bf2f_hi(hv.y);
        s += v0 * as[g * 4 + 0] + v1 * as[g * 4 + 1] + v2 * as[g * 4 + 2] + v3 * as[g * 4 + 3];
        d += v0 * ad[g * 4 + 0] + v1 * ad[g * 4 + 1] + v2 * ad[g * 4 + 2] + v3 * ad[g * 4 + 3];
    }
    (dir ? asrc_out : asrc_in)[idx] = s;
    (dir ? adst_out : adst_in)[idx] = d;
}

// ---------------------------------------------------------------------------
// CSR build: zero -> histogram -> scan (3 stages) -> scatter adjacency
// ---------------------------------------------------------------------------
__global__ __launch_bounds__(256) void zero_cnt_kernel(int* __restrict__ cnt_in,
                                                       int* __restrict__ cnt_out)
{
    const int i = blockIdx.x * 256 + threadIdx.x;
    if (i < N_NODES) { cnt_in[i] = 0; cnt_out[i] = 0; }
}

__global__ __launch_bounds__(256) void hist_kernel(const int* __restrict__ ei,
                                                   int* __restrict__ cnt_in,
                                                   int* __restrict__ cnt_out)
{
    const int e = blockIdx.x * 256 + threadIdx.x;
    if (e >= N_EDGES) return;
    const int s = ei[e];
    const int t = ei[N_EDGES + e];
    atomicAdd(&cnt_in[t], 1);
    atomicAdd(&cnt_out[s], 1);
}

__global__ __launch_bounds__(SCAN_B) void scan1_kernel(
    const int* __restrict__ cnt_in, const int* __restrict__ cnt_out,
    int* __restrict__ pre_in, int* __restrict__ pre_out,
    int* __restrict__ part_in, int* __restrict__ part_out)
{
    const int dir = blockIdx.y;
    const int* cnt = dir ? cnt_out : cnt_in;
    int* pre  = dir ? pre_out  : pre_in;
    int* part = dir ? part_out : part_in;

    __shared__ int sm[SCAN_B];
    const int tid = threadIdx.x;
    const int i = blockIdx.x * SCAN_B + tid;
    const int v = (i < N_NODES) ? cnt[i] : 0;
    sm[tid] = v;
    __syncthreads();
#pragma unroll
    for (int off = 1; off < SCAN_B; off <<= 1) {
        int t = (tid >= off) ? sm[tid - off] : 0;
        __syncthreads();
        sm[tid] += t;
        __syncthreads();
    }
    if (i < N_NODES) pre[i] = sm[tid] - v;
    if (tid == SCAN_B - 1) part[blockIdx.x] = sm[tid];
}

__global__ __launch_bounds__(512) void scan2_kernel(int* __restrict__ part_in,
                                                    int* __restrict__ part_out)
{
    const int dir = blockIdx.x;
    int* part = dir ? part_out : part_in;
    __shared__ int sm[512];
    const int tid = threadIdx.x;
    const int v = (tid < SCAN_NB) ? part[tid] : 0;
    sm[tid] = v;
    __syncthreads();
#pragma unroll
    for (int off = 1; off < 512; off <<= 1) {
        int t = (tid >= off) ? sm[tid - off] : 0;
        __syncthreads();
        sm[tid] += t;
        __syncthreads();
    }
    if (tid < SCAN_NB) part[tid] = sm[tid] - v;
}

__global__ __launch_bounds__(SCAN_B) void scan3_kernel(
    const int* __restrict__ pre_in, const int* __restrict__ pre_out,
    const int* __restrict__ part_in, const int* __restrict__ part_out,
    int* __restrict__ offs_in, int* __restrict__ offs_out,
    int* __restrict__ cur_in, int* __restrict__ cur_out)
{
    const int dir = blockIdx.y;
    const int* pre  = dir ? pre_out  : pre_in;
    const int* part = dir ? part_out : part_in;
    int* offs = dir ? offs_out : offs_in;
    int* cur  = dir ? cur_out  : cur_in;

    const int i = blockIdx.x * SCAN_B + threadIdx.x;
    if (i < N_NODES) {
        const int o = pre[i] + part[blockIdx.x];
        offs[i] = o;
        cur[i]  = o;
    }
    if (i == 0 && dir == 0) { offs_in[N_NODES] = N_EDGES; offs_out[N_NODES] = N_EDGES; }
}

__global__ __launch_bounds__(256) void scatter_adj_kernel(
    const int* __restrict__ ei,
    int* __restrict__ cur_in, int* __restrict__ cur_out,
    int* __restrict__ adj_in, int* __restrict__ adj_out)
{
    const int e = blockIdx.x * 256 + threadIdx.x;
    if (e >= N_EDGES) return;
    const int s = ei[e];
    const int t = ei[N_EDGES + e];
    adj_in[atomicAdd(&cur_in[t], 1)]  = s;
    adj_out[atomicAdd(&cur_out[s], 1)] = t;
}

// ---------------------------------------------------------------------------
// Gather: one wave per node, both directions + bias. h is bf16. No atomics.
// ---------------------------------------------------------------------------
__global__ __launch_bounds__(256) void gather_kernel(
    const int* __restrict__ offs_in, const int* __restrict__ adj_in,
    const int* __restrict__ offs_out, const int* __restrict__ adj_out,
    const unsigned short* __restrict__ h_in, const unsigned short* __restrict__ h_out,
    const float* __restrict__ asrc_in, const float* __restrict__ adst_in,
    const float* __restrict__ asrc_out, const float* __restrict__ adst_out,
    const float* __restrict__ b_in, const float* __restrict__ b_out,
    float* __restrict__ out)
{
    const int n = (blockIdx.x * 256 + threadIdx.x) >> 6;
    if (n >= N_NODES) return;
    const int lane = threadIdx.x & 63;
    const int c0 = lane * 2;
    const int hh = lane >> 3;

    float acc0 = b_in[c0] + b_out[c0];
    float acc1 = b_in[c0 + 1] + b_out[c0 + 1];

    {
        const int beg = offs_in[n], end = offs_in[n + 1];
        if (end > beg) {
            const float ad = adst_in[n * 8 + hh];
            float num0 = 0.f, num1 = 0.f, den = 0.f;
            for (int p = beg; p < end; ++p) {
                const int nbr = adj_in[p];
                float l = asrc_in[nbr * 8 + hh] + ad;
                l = l > 0.f ? l : NEG * l;
                const float w = __expf(l);
                den += w;
                const unsigned hv = *(const unsigned*)&h_in[(long long)nbr * 128 + c0];
                num0 += w * bf2f_lo(hv);
                num1 += w * bf2f_hi(hv);
            }
            acc0 += num0 / den;
            acc1 += num1 / den;
        }
    }
    {
        const int beg = offs_out[n], end = offs_out[n + 1];
        if (end > beg) {
            const float ad = adst_out[n * 8 + hh];
            float num0 = 0.f, num1 = 0.f, den = 0.f;
            for (int p = beg; p < end; ++p) {
                const int nbr = adj_out[p];
                float l = asrc_out[nbr * 8 + hh] + ad;
                l = l > 0.f ? l : NEG * l;
                const float w = __expf(l);
                den += w;
                const unsigned hv = *(const unsigned*)&h_out[(long long)nbr * 128 + c0];
                num0 += w * bf2f_lo(hv);
                num1 += w * bf2f_hi(hv);
            }
            acc0 += num0 / den;
            acc1 += num1 / den;
        }
    }
    *(float2*)&out[(long long)n * 128 + c0] = float2{acc0, acc1};
}

extern "C" void kernel_launch(void* const* d_in, const int* in_sizes, int n_in,
                              void* d_out, int out_size, void* d_ws, size_t ws_size,
                              hipStream_t stream) {
    const float* x      = (const float*)d_in[0];
    const int*   ei     = (const int*)  d_in[1];
    const float* W_in   = (const float*)d_in[2];
    const float* as_in  = (const float*)d_in[3];
    const float* ad_in  = (const float*)d_in[4];
    const float* b_in   = (const float*)d_in[5];
    const float* W_out  = (const float*)d_in[6];
    const float* as_out = (const float*)d_in[7];
    const float* ad_out = (const float*)d_in[8];
    const float* b_out  = (const float*)d_in[9];
    float* out = (float*)d_out;

    // workspace layout
    char* ws = (char*)d_ws;
    const long long NH = (long long)N_NODES * 128;
    unsigned short* h_in  = (unsigned short*)ws;    ws += NH * 2;
    unsigned short* h_out = (unsigned short*)ws;    ws += NH * 2;
    float* asrc_in   = (float*)ws;                  ws += N_NODES * 8 * 4;
    float* adst_in   = (float*)ws;                  ws += N_NODES * 8 * 4;
    float* asrc_out  = (float*)ws;                  ws += N_NODES * 8 * 4;
    float* adst_out  = (float*)ws;                  ws += N_NODES * 8 * 4;
    int* adj_in      = (int*)ws;                    ws += N_EDGES * 4;
    int* adj_out     = (int*)ws;                    ws += N_EDGES * 4;
    int* offs_in     = (int*)ws;                    ws += (N_NODES + 1) * 4;
    int* offs_out    = (int*)ws;                    ws += (N_NODES + 1) * 4;
    int* cnt_in      = (int*)ws;                    ws += N_NODES * 4;   // reused as cursors
    int* cnt_out     = (int*)ws;                    ws += N_NODES * 4;
    int* pre_in      = (int*)ws;                    ws += N_NODES * 4;
    int* pre_out     = (int*)ws;                    ws += N_NODES * 4;
    int* part_in     = (int*)ws;                    ws += SCAN_NB * 4;
    int* part_out    = (int*)ws;                    ws += SCAN_NB * 4;

    dim3 gemm_grid((N_NODES + 127) / 128, 2);
    gemm_kernel<<<gemm_grid, 256, 0, stream>>>(x, W_in, W_out, h_in, h_out);

    dim3 alpha_grid((N_NODES * 8 + 255) / 256, 2);
    alpha_kernel<<<alpha_grid, 256, 0, stream>>>(
        h_in, h_out, as_in, ad_in, as_out, ad_out,
        asrc_in, adst_in, asrc_out, adst_out);

    zero_cnt_kernel<<<(N_NODES + 255) / 256, 256, 0, stream>>>(cnt_in, cnt_out);
    hist_kernel<<<(N_EDGES + 255) / 256, 256, 0, stream>>>(ei, cnt_in, cnt_out);
    scan1_kernel<<<dim3(SCAN_NB, 2), SCAN_B, 0, stream>>>(
        cnt_in, cnt_out, pre_in, pre_out, part_in, part_out);
    scan2_kernel<<<2, 512, 0, stream>>>(part_in, part_out);
    scan3_kernel<<<dim3(SCAN_NB, 2), SCAN_B, 0, stream>>>(
        pre_in, pre_out, part_in, part_out, offs_in, offs_out, cnt_in, cnt_out);
    scatter_adj_kernel<<<(N_EDGES + 255) / 256, 256, 0, stream>>>(
        ei, cnt_in, cnt_out, adj_in, adj_out);

    gather_kernel<<<(N_NODES * 64 + 255) / 256, 256, 0, stream>>>(
        offs_in, adj_in, offs_out, adj_out, h_in, h_out,
        asrc_in, adst_in, asrc_out, adst_out, b_in, b_out, out);
}

// Round 4
// 458.175 us; speedup vs baseline: 2.2319x; 1.1605x over previous
//
#include <hip/hip_runtime.h>

#define N_NODES 100000
#define N_EDGES 800000
#define NEG 0.2f
#define SCAN_B 256
#define SCAN_NB ((N_NODES + SCAN_B - 1) / SCAN_B)   // 391

typedef __attribute__((ext_vector_type(8))) short bf16x8;
typedef __attribute__((ext_vector_type(4))) float f32x4;

__device__ inline unsigned short f2bf(float f) {   // RNE f32 -> bf16
    unsigned u = __float_as_uint(f);
    u += 0x7fffu + ((u >> 16) & 1u);
    return (unsigned short)(u >> 16);
}
__device__ inline float bf2f_lo(unsigned u) { return __uint_as_float(u << 16); }
__device__ inline float bf2f_hi(unsigned u) { return __uint_as_float(u & 0xffff0000u); }

// ---------------------------------------------------------------------------
// prep_x: x f32 -> bf16 (shared by both GEMM directions)
// ---------------------------------------------------------------------------
__global__ __launch_bounds__(256) void prep_x_kernel(
    const float* __restrict__ x, unsigned short* __restrict__ x_bf)
{
    const int i = (blockIdx.x * 256 + threadIdx.x) * 4;
    if (i >= N_NODES * 128) return;
    const float4 v = *(const float4*)&x[i];
    ushort4 o;
    o.x = f2bf(v.x); o.y = f2bf(v.y); o.z = f2bf(v.z); o.w = f2bf(v.w);
    *(ushort4*)&x_bf[i] = o;
}

// ---------------------------------------------------------------------------
// prep_w: pack W (and Aalpha = W·a vectors, ct==8) into MFMA B-fragment order.
// Frag f = ((dir*4+kb)*9+ct)*64+lane holds B[k=kb*32+quad*8+j][n] for j=0..7,
// where n = ct*16+m16 (ct<8) or alpha column m16 (ct==8: m16<8 -> src head,
// m16>=8 -> dst head). One thread per fragment (2*4*9*64 = 4608 threads).
// ---------------------------------------------------------------------------
__global__ __launch_bounds__(256) void prep_w_kernel(
    const float* __restrict__ W_in, const float* __restrict__ W_out,
    const float* __restrict__ as_in, const float* __restrict__ ad_in,
    const float* __restrict__ as_out, const float* __restrict__ ad_out,
    unsigned short* __restrict__ Wf)
{
    const int t = blockIdx.x * 256 + threadIdx.x;
    if (t >= 2 * 4 * 9 * 64) return;
    const int lane = t & 63;
    const int rest = t >> 6;
    const int ct  = rest % 9;
    const int kb  = (rest / 9) & 3;
    const int dir = rest / 36;
    const float* W  = dir ? W_out  : W_in;
    const float* as = dir ? as_out : as_in;
    const float* ad = dir ? ad_out : ad_in;
    const int m16 = lane & 15, quad = lane >> 4;

    bf16x8 o;
#pragma unroll
    for (int j = 0; j < 8; ++j) {
        const int k = kb * 32 + quad * 8 + j;
        float v;
        if (ct < 8) {
            v = W[k * 128 + ct * 16 + m16];
        } else {
            const float* av = (m16 < 8) ? as : ad;
            const int hh = m16 & 7;
            v = 0.f;
            for (int c = 0; c < 16; ++c)
                v += W[k * 128 + hh * 16 + c] * av[hh * 16 + c];
        }
        o[j] = (short)f2bf(v);
    }
    *(bf16x8*)&Wf[(long long)t * 8] = o;
}

// ---------------------------------------------------------------------------
// gemm: h = bf16(x) @ bf16(W) via MFMA; alpha logits come out of the 9th
// column tile. No LDS, no barriers: W fragments stream from L1/L2.
// grid = (782, 2 dirs), block 256 (4 waves, each 32 rows = 2 A-tiles).
// C/D layout: col = lane&15, row = (lane>>4)*4 + reg.
// ---------------------------------------------------------------------------
__global__ __launch_bounds__(256) void gemm_kernel(
    const unsigned short* __restrict__ x_bf,
    const unsigned short* __restrict__ Wf,
    unsigned short* __restrict__ h_in, unsigned short* __restrict__ h_out,
    float* __restrict__ asrc_in, float* __restrict__ adst_in,
    float* __restrict__ asrc_out, float* __restrict__ adst_out)
{
    const int dir = blockIdx.y;
    unsigned short* h = dir ? h_out : h_in;
    float* asrc = dir ? asrc_out : asrc_in;
    float* adst = dir ? adst_out : adst_in;

    const int tid  = threadIdx.x;
    const int lane = tid & 63;
    const int wave = tid >> 6;
    const int m16  = lane & 15;
    const int quad = lane >> 4;
    const int rbase = blockIdx.x * 128 + wave * 32;

    f32x4 acc[2][8];
    f32x4 acc_a[2];
#pragma unroll
    for (int rt = 0; rt < 2; ++rt) {
        acc_a[rt] = f32x4{0.f, 0.f, 0.f, 0.f};
#pragma unroll
        for (int ct = 0; ct < 8; ++ct)
            acc[rt][ct] = f32x4{0.f, 0.f, 0.f, 0.f};
    }

    const unsigned short* wf = Wf + (long long)dir * 4 * 9 * 64 * 8;

#pragma unroll
    for (int kb = 0; kb < 4; ++kb) {
        const int k0 = kb * 32 + quad * 8;
        bf16x8 a[2];
#pragma unroll
        for (int rt = 0; rt < 2; ++rt) {
            int r = rbase + rt * 16 + m16;
            r = r < N_NODES ? r : N_NODES - 1;   // clamp: OOB rows compute garbage, stores guarded
            a[rt] = *(const bf16x8*)&x_bf[(long long)r * 128 + k0];
        }
#pragma unroll
        for (int ct = 0; ct < 9; ++ct) {
            const bf16x8 b = *(const bf16x8*)&wf[(long long)((kb * 9 + ct) * 64 + lane) * 8];
            if (ct < 8) {
                acc[0][ct] = __builtin_amdgcn_mfma_f32_16x16x32_bf16(a[0], b, acc[0][ct], 0, 0, 0);
                acc[1][ct] = __builtin_amdgcn_mfma_f32_16x16x32_bf16(a[1], b, acc[1][ct], 0, 0, 0);
            } else {
                acc_a[0] = __builtin_amdgcn_mfma_f32_16x16x32_bf16(a[0], b, acc_a[0], 0, 0, 0);
                acc_a[1] = __builtin_amdgcn_mfma_f32_16x16x32_bf16(a[1], b, acc_a[1], 0, 0, 0);
            }
        }
    }

#pragma unroll
    for (int rt = 0; rt < 2; ++rt) {
#pragma unroll
        for (int r = 0; r < 4; ++r) {
            const int row = rbase + rt * 16 + quad * 4 + r;
            if (row < N_NODES) {
                unsigned short* hp = &h[(long long)row * 128 + m16];
#pragma unroll
                for (int ct = 0; ct < 8; ++ct)
                    hp[ct * 16] = f2bf(acc[rt][ct][r]);
                const float av = acc_a[rt][r];
                if (m16 < 8) asrc[row * 8 + m16] = av;
                else         adst[row * 8 + (m16 - 8)] = av;
            }
        }
    }
}

// ---------------------------------------------------------------------------
// CSR build: zero -> histogram -> scan (3 stages) -> scatter adjacency
// ---------------------------------------------------------------------------
__global__ __launch_bounds__(256) void zero_cnt_kernel(int* __restrict__ cnt_in,
                                                       int* __restrict__ cnt_out)
{
    const int i = blockIdx.x * 256 + threadIdx.x;
    if (i < N_NODES) { cnt_in[i] = 0; cnt_out[i] = 0; }
}

__global__ __launch_bounds__(256) void hist_kernel(const int* __restrict__ ei,
                                                   int* __restrict__ cnt_in,
                                                   int* __restrict__ cnt_out)
{
    const int e = blockIdx.x * 256 + threadIdx.x;
    if (e >= N_EDGES) return;
    const int s = ei[e];
    const int t = ei[N_EDGES + e];
    atomicAdd(&cnt_in[t], 1);
    atomicAdd(&cnt_out[s], 1);
}

__global__ __launch_bounds__(SCAN_B) void scan1_kernel(
    const int* __restrict__ cnt_in, const int* __restrict__ cnt_out,
    int* __restrict__ pre_in, int* __restrict__ pre_out,
    int* __restrict__ part_in, int* __restrict__ part_out)
{
    const int dir = blockIdx.y;
    const int* cnt = dir ? cnt_out : cnt_in;
    int* pre  = dir ? pre_out  : pre_in;
    int* part = dir ? part_out : part_in;

    __shared__ int sm[SCAN_B];
    const int tid = threadIdx.x;
    const int i = blockIdx.x * SCAN_B + tid;
    const int v = (i < N_NODES) ? cnt[i] : 0;
    sm[tid] = v;
    __syncthreads();
#pragma unroll
    for (int off = 1; off < SCAN_B; off <<= 1) {
        int t = (tid >= off) ? sm[tid - off] : 0;
        __syncthreads();
        sm[tid] += t;
        __syncthreads();
    }
    if (i < N_NODES) pre[i] = sm[tid] - v;
    if (tid == SCAN_B - 1) part[blockIdx.x] = sm[tid];
}

__global__ __launch_bounds__(512) void scan2_kernel(int* __restrict__ part_in,
                                                    int* __restrict__ part_out)
{
    const int dir = blockIdx.x;
    int* part = dir ? part_out : part_in;
    __shared__ int sm[512];
    const int tid = threadIdx.x;
    const int v = (tid < SCAN_NB) ? part[tid] : 0;
    sm[tid] = v;
    __syncthreads();
#pragma unroll
    for (int off = 1; off < 512; off <<= 1) {
        int t = (tid >= off) ? sm[tid - off] : 0;
        __syncthreads();
        sm[tid] += t;
        __syncthreads();
    }
    if (tid < SCAN_NB) part[tid] = sm[tid] - v;
}

__global__ __launch_bounds__(SCAN_B) void scan3_kernel(
    const int* __restrict__ pre_in, const int* __restrict__ pre_out,
    const int* __restrict__ part_in, const int* __restrict__ part_out,
    int* __restrict__ offs_in, int* __restrict__ offs_out,
    int* __restrict__ cur_in, int* __restrict__ cur_out)
{
    const int dir = blockIdx.y;
    const int* pre  = dir ? pre_out  : pre_in;
    const int* part = dir ? part_out : part_in;
    int* offs = dir ? offs_out : offs_in;
    int* cur  = dir ? cur_out  : cur_in;

    const int i = blockIdx.x * SCAN_B + threadIdx.x;
    if (i < N_NODES) {
        const int o = pre[i] + part[blockIdx.x];
        offs[i] = o;
        cur[i]  = o;
    }
    if (i == 0 && dir == 0) { offs_in[N_NODES] = N_EDGES; offs_out[N_NODES] = N_EDGES; }
}

__global__ __launch_bounds__(256) void scatter_adj_kernel(
    const int* __restrict__ ei,
    int* __restrict__ cur_in, int* __restrict__ cur_out,
    int* __restrict__ adj_in, int* __restrict__ adj_out)
{
    const int e = blockIdx.x * 256 + threadIdx.x;
    if (e >= N_EDGES) return;
    const int s = ei[e];
    const int t = ei[N_EDGES + e];
    adj_in[atomicAdd(&cur_in[t], 1)]  = s;
    adj_out[atomicAdd(&cur_out[s], 1)] = t;
}

// ---------------------------------------------------------------------------
// Gather: one wave per node, both directions + bias, unrolled x4 for MLP.
// ---------------------------------------------------------------------------
__global__ __launch_bounds__(256) void gather_kernel(
    const int* __restrict__ offs_in, const int* __restrict__ adj_in,
    const int* __restrict__ offs_out, const int* __restrict__ adj_out,
    const unsigned short* __restrict__ h_in, const unsigned short* __restrict__ h_out,
    const float* __restrict__ asrc_in, const float* __restrict__ adst_in,
    const float* __restrict__ asrc_out, const float* __restrict__ adst_out,
    const float* __restrict__ b_in, const float* __restrict__ b_out,
    float* __restrict__ out)
{
    const int n = (blockIdx.x * 256 + threadIdx.x) >> 6;
    if (n >= N_NODES) return;
    const int lane = threadIdx.x & 63;
    const int c0 = lane * 2;
    const int hh = lane >> 3;

    float acc0 = b_in[c0] + b_out[c0];
    float acc1 = b_in[c0 + 1] + b_out[c0 + 1];

#define DIR_BLOCK(OFFS, ADJ, HX, ASRC, ADST)                                   \
    {                                                                          \
        const int beg = OFFS[n], end = OFFS[n + 1];                            \
        if (end > beg) {                                                       \
            const float ad = ADST[n * 8 + hh];                                 \
            float num0 = 0.f, num1 = 0.f, den = 0.f;                           \
            int p = beg;                                                       \
            for (; p + 4 <= end; p += 4) {                                     \
                const int nb0 = ADJ[p], nb1 = ADJ[p + 1];                      \
                const int nb2 = ADJ[p + 2], nb3 = ADJ[p + 3];                  \
                const float s0 = ASRC[nb0 * 8 + hh], s1 = ASRC[nb1 * 8 + hh];  \
                const float s2 = ASRC[nb2 * 8 + hh], s3 = ASRC[nb3 * 8 + hh];  \
                const unsigned v0 = *(const unsigned*)&HX[(long long)nb0 * 128 + c0]; \
                const unsigned v1 = *(const unsigned*)&HX[(long long)nb1 * 128 + c0]; \
                const unsigned v2 = *(const unsigned*)&HX[(long long)nb2 * 128 + c0]; \
                const unsigned v3 = *(const unsigned*)&HX[(long long)nb3 * 128 + c0]; \
                float l0 = s0 + ad; l0 = l0 > 0.f ? l0 : NEG * l0;             \
                float l1 = s1 + ad; l1 = l1 > 0.f ? l1 : NEG * l1;             \
                float l2 = s2 + ad; l2 = l2 > 0.f ? l2 : NEG * l2;             \
                float l3 = s3 + ad; l3 = l3 > 0.f ? l3 : NEG * l3;             \
                const float w0 = __expf(l0), w1 = __expf(l1);                  \
                const float w2 = __expf(l2), w3 = __expf(l3);                  \
                den += (w0 + w1) + (w2 + w3);                                  \
                num0 += w0 * bf2f_lo(v0) + w1 * bf2f_lo(v1)                    \
                      + w2 * bf2f_lo(v2) + w3 * bf2f_lo(v3);                   \
                num1 += w0 * bf2f_hi(v0) + w1 * bf2f_hi(v1)                    \
                      + w2 * bf2f_hi(v2) + w3 * bf2f_hi(v3);                   \
            }                                                                  \
            for (; p < end; ++p) {                                             \
                const int nb = ADJ[p];                                         \
                float l = ASRC[nb * 8 + hh] + ad;                              \
                l = l > 0.f ? l : NEG * l;                                     \
                const float w = __expf(l);                                     \
                den += w;                                                      \
                const unsigned hv = *(const unsigned*)&HX[(long long)nb * 128 + c0]; \
                num0 += w * bf2f_lo(hv);                                       \
                num1 += w * bf2f_hi(hv);                                       \
            }                                                                  \
            acc0 += num0 / den;                                                \
            acc1 += num1 / den;                                                \
        }                                                                      \
    }

    DIR_BLOCK(offs_in, adj_in, h_in, asrc_in, adst_in)
    DIR_BLOCK(offs_out, adj_out, h_out, asrc_out, adst_out)
#undef DIR_BLOCK

    *(float2*)&out[(long long)n * 128 + c0] = float2{acc0, acc1};
}

extern "C" void kernel_launch(void* const* d_in, const int* in_sizes, int n_in,
                              void* d_out, int out_size, void* d_ws, size_t ws_size,
                              hipStream_t stream) {
    const float* x      = (const float*)d_in[0];
    const int*   ei     = (const int*)  d_in[1];
    const float* W_in   = (const float*)d_in[2];
    const float* as_in  = (const float*)d_in[3];
    const float* ad_in  = (const float*)d_in[4];
    const float* b_in   = (const float*)d_in[5];
    const float* W_out  = (const float*)d_in[6];
    const float* as_out = (const float*)d_in[7];
    const float* ad_out = (const float*)d_in[8];
    const float* b_out  = (const float*)d_in[9];
    float* out = (float*)d_out;

    // workspace layout (16B-aligned carve)
    char* ws = (char*)d_ws;
    const long long NH = (long long)N_NODES * 128;
    unsigned short* x_bf  = (unsigned short*)ws;    ws += NH * 2;
    unsigned short* h_in  = (unsigned short*)ws;    ws += NH * 2;
    unsigned short* h_out = (unsigned short*)ws;    ws += NH * 2;
    unsigned short* Wf    = (unsigned short*)ws;    ws += 2LL * 4 * 9 * 64 * 8 * 2;
    float* asrc_in   = (float*)ws;                  ws += N_NODES * 8 * 4;
    float* adst_in   = (float*)ws;                  ws += N_NODES * 8 * 4;
    float* asrc_out  = (float*)ws;                  ws += N_NODES * 8 * 4;
    float* adst_out  = (float*)ws;                  ws += N_NODES * 8 * 4;
    int* adj_in      = (int*)ws;                    ws += N_EDGES * 4;
    int* adj_out     = (int*)ws;                    ws += N_EDGES * 4;
    int* offs_in     = (int*)ws;                    ws += (N_NODES + 1) * 4;
    int* offs_out    = (int*)ws;                    ws += (N_NODES + 1) * 4;
    int* cnt_in      = (int*)ws;                    ws += N_NODES * 4;   // reused as cursors
    int* cnt_out     = (int*)ws;                    ws += N_NODES * 4;
    int* pre_in      = (int*)ws;                    ws += N_NODES * 4;
    int* pre_out     = (int*)ws;                    ws += N_NODES * 4;
    int* part_in     = (int*)ws;                    ws += SCAN_NB * 4;
    int* part_out    = (int*)ws;                    ws += SCAN_NB * 4;

    prep_x_kernel<<<(N_NODES * 128 / 4 + 255) / 256, 256, 0, stream>>>(x, x_bf);
    prep_w_kernel<<<(2 * 4 * 9 * 64 + 255) / 256, 256, 0, stream>>>(
        W_in, W_out, as_in, ad_in, as_out, ad_out, Wf);

    dim3 gemm_grid((N_NODES + 127) / 128, 2);
    gemm_kernel<<<gemm_grid, 256, 0, stream>>>(
        x_bf, Wf, h_in, h_out, asrc_in, adst_in, asrc_out, adst_out);

    zero_cnt_kernel<<<(N_NODES + 255) / 256, 256, 0, stream>>>(cnt_in, cnt_out);
    hist_kernel<<<(N_EDGES + 255) / 256, 256, 0, stream>>>(ei, cnt_in, cnt_out);
    scan1_kernel<<<dim3(SCAN_NB, 2), SCAN_B, 0, stream>>>(
        cnt_in, cnt_out, pre_in, pre_out, part_in, part_out);
    scan2_kernel<<<2, 512, 0, stream>>>(part_in, part_out);
    scan3_kernel<<<dim3(SCAN_NB, 2), SCAN_B, 0, stream>>>(
        pre_in, pre_out, part_in, part_out, offs_in, offs_out, cnt_in, cnt_out);
    scatter_adj_kernel<<<(N_EDGES + 255) / 256, 256, 0, stream>>>(
        ei, cnt_in, cnt_out, adj_in, adj_out);

    gather_kernel<<<(N_NODES * 64 + 255) / 256, 256, 0, stream>>>(
        offs_in, adj_in, offs_out, adj_out, h_in, h_out,
        asrc_in, adst_in, asrc_out, adst_out, b_in, b_out, out);
}